// Round 11
// baseline (1062.039 us; speedup 1.0000x reference)
//
#include <hip/hip_runtime.h>
#include <hip/hip_fp16.h>

#define NB   256
#define TT   1024
#define II   64
#define NT   512

typedef _Float16 f16;
typedef _Float16 hf8 __attribute__((ext_vector_type(8)));
typedef float    ff4 __attribute__((ext_vector_type(4)));

__device__ __forceinline__ float rcp_fast(float x){
    float r; asm("v_rcp_f32 %0, %1" : "=v"(r) : "v"(x)); return r;
}
__device__ __forceinline__ float exp2_fast(float x){
    float r; asm("v_exp_f32 %0, %1" : "=v"(r) : "v"(x)); return r;
}
__device__ __forceinline__ float sigm(float x){
    return rcp_fast(1.0f + exp2_fast(x * -1.44269504f));
}
__device__ __forceinline__ float tanh_f(float x){
    return fmaf(-2.0f, rcp_fast(1.0f + exp2_fast(x * 2.88539008f)), 1.0f);
}
__device__ __forceinline__ hf8 cvt8(float4 a, float4 b){
    hf8 r;
    r[0]=(f16)a.x; r[1]=(f16)a.y; r[2]=(f16)a.z; r[3]=(f16)a.w;
    r[4]=(f16)b.x; r[5]=(f16)b.y; r[6]=(f16)b.z; r[7]=(f16)b.w;
    return r;
}
__device__ __forceinline__ hf8 ldw8(const float* src){
    float4 v0 = *(const float4*)src;
    float4 v1 = *(const float4*)(src + 4);
    return cvt8(v0, v1);
}

// Gate-interleaved tiles (verified R5-R10): tile row rho' <-> gate-row
// R = (rho'&3)*H + 4*tau + (rho'>>2); C/D row = kg*4+reg => lane (kg,rho)
// holds gates i,f,g,o of unit 4*tau+kg in one ff4.
// Waves 0-3: L1, 8 tiles (8w+i), K = h1 only (4 kt). acc init = xg ds_read.
// Waves 4-7: L2, 4 tiles, K = [h1(4);h2(2)] (6 kt). acc init = bias2.
// All waves: chunk GEMM, 4 Wih1 M-tiles (4w+i) x K=64 (2 kkt), cols = 16
// timesteps (rho). xg[16][128][4] f32, bank-swizzle u^(row&7), single-buffered
// with an extra barrier on GEMM steps (t%16==15). x: global->regs at t%16==14.

__launch_bounds__(NT, 2)
__global__ void lstm_mfma(const float* __restrict__ x,
                          const float* __restrict__ Wih1, const float* __restrict__ Whh1,
                          const float* __restrict__ bih1, const float* __restrict__ bhh1,
                          const float* __restrict__ Wih2, const float* __restrict__ Whh2,
                          const float* __restrict__ bih2, const float* __restrict__ bhh2,
                          const float* __restrict__ W1,   const float* __restrict__ b1,
                          const float* __restrict__ W2,   const float* __restrict__ b2,
                          float* __restrict__ out)
{
    __shared__ __align__(16) float xg[16][128][4];   // 32 KB
    __shared__ __align__(16) f16 h1buf[2][128];
    __shared__ __align__(16) f16 h2buf[2][64];
    __shared__ float headbuf[32];

    const int j    = threadIdx.x;      // 0..511
    const int b    = blockIdx.x;
    const int wave = j >> 6;           // 0..7
    const int lane = j & 63;
    const int rho  = lane & 15;
    const int kg   = lane >> 4;
    const bool l2w = (wave >= 4);

    const float* xb = x + (size_t)b * TT * II;

    // issue chunk-0 x loads first (latency covered by weight loading)
    float4 xl0, xl1, xl2, xl3;
    {
        const float* xp = xb + (size_t)rho * II + kg*8;
        xl0 = *(const float4*)xp;
        xl1 = *(const float4*)(xp + 4);
        xl2 = *(const float4*)(xp + 32);
        xl3 = *(const float4*)(xp + 36);
    }

    // ---------- weights ----------
    hf8 A[32];                          // L1: A[i*4+kt] i<8 | L2: A[i*6+kt] i<4
    if (!l2w){
        #pragma unroll
        for (int i = 0; i < 8; ++i){
            const int tau = 8*wave + i;
            const int R   = (rho & 3)*128 + 4*tau + (rho >> 2);
            #pragma unroll
            for (int kt = 0; kt < 4; ++kt)
                A[i*4 + kt] = ldw8(Whh1 + R*128 + 32*kt + kg*8);
        }
    } else {
        #pragma unroll
        for (int i = 0; i < 4; ++i){
            const int tau2 = 4*(wave - 4) + i;
            const int R    = (rho & 3)*64 + 4*tau2 + (rho >> 2);
            #pragma unroll
            for (int kt = 0; kt < 6; ++kt)
                A[i*6 + kt] = ldw8((kt < 4) ? (Wih2 + R*128 + 32*kt + kg*8)
                                            : (Whh2 + R*64  + 32*(kt-4) + kg*8));
        }
    }
    hf8 AX[8];
    ff4 biasX[4];
    #pragma unroll
    for (int i = 0; i < 4; ++i){
        const int tau = 4*wave + i;
        const int R   = (rho & 3)*128 + 4*tau + (rho >> 2);
        #pragma unroll
        for (int kkt = 0; kkt < 2; ++kkt)
            AX[i*2 + kkt] = ldw8(Wih1 + R*64 + 32*kkt + kg*8);
        #pragma unroll
        for (int r = 0; r < 4; ++r){
            const int Rb = r*128 + 4*tau + kg;
            biasX[i][r] = bih1[Rb] + bhh1[Rb];
        }
    }
    ff4 bias2[4];
    if (l2w){
        #pragma unroll
        for (int i = 0; i < 4; ++i)
            #pragma unroll
            for (int r = 0; r < 4; ++r){
                const int Rb = r*64 + 4*(4*(wave-4) + i) + kg;
                bias2[i][r] = bih2[Rb] + bhh2[Rb];
            }
    }

    if (j < 128) h1buf[0][j] = (f16)0.0f;
    if (j < 64)  h2buf[0][j] = (f16)0.0f;

    // ---------- prologue GEMM: xg for chunk 0 ----------
    {
        hf8 xh0 = cvt8(xl0, xl1);
        hf8 xh1 = cvt8(xl2, xl3);
        ff4 g0 = biasX[0], g1 = biasX[1], g2 = biasX[2], g3 = biasX[3];
        g0 = __builtin_amdgcn_mfma_f32_16x16x32_f16(AX[0], xh0, g0, 0, 0, 0);
        g1 = __builtin_amdgcn_mfma_f32_16x16x32_f16(AX[2], xh0, g1, 0, 0, 0);
        g2 = __builtin_amdgcn_mfma_f32_16x16x32_f16(AX[4], xh0, g2, 0, 0, 0);
        g3 = __builtin_amdgcn_mfma_f32_16x16x32_f16(AX[6], xh0, g3, 0, 0, 0);
        g0 = __builtin_amdgcn_mfma_f32_16x16x32_f16(AX[1], xh1, g0, 0, 0, 0);
        g1 = __builtin_amdgcn_mfma_f32_16x16x32_f16(AX[3], xh1, g1, 0, 0, 0);
        g2 = __builtin_amdgcn_mfma_f32_16x16x32_f16(AX[5], xh1, g2, 0, 0, 0);
        g3 = __builtin_amdgcn_mfma_f32_16x16x32_f16(AX[7], xh1, g3, 0, 0, 0);
        const int sw = rho & 7;
        *(ff4*)&xg[rho][(4*(4*wave+0)+kg) ^ sw][0] = g0;
        *(ff4*)&xg[rho][(4*(4*wave+1)+kg) ^ sw][0] = g1;
        *(ff4*)&xg[rho][(4*(4*wave+2)+kg) ^ sw][0] = g2;
        *(ff4*)&xg[rho][(4*(4*wave+3)+kg) ^ sw][0] = g3;
    }
    __syncthreads();

    float c = 0.0f;
    int cur = 0;
    for (int t = 0; t < TT; ++t){
        const int trow = t & 15;

        // issue next chunk's x loads (held 1 step, ~1100cyc > HBM latency)
        if (trow == 14 && t + 2 < TT){
            const float* xp = xb + (size_t)(t + 2 + rho) * II + kg*8;
            xl0 = *(const float4*)xp;
            xl1 = *(const float4*)(xp + 4);
            xl2 = *(const float4*)(xp + 32);
            xl3 = *(const float4*)(xp + 36);
        }

        const f16* h1c = h1buf[cur];
        const f16* h2c = h2buf[cur];
        const int  sx  = trow & 7;

        hf8 bf0 = *(const hf8*)(h1c      + kg*8);
        hf8 bf1 = *(const hf8*)(h1c + 32 + kg*8);
        hf8 bf2 = *(const hf8*)(h1c + 64 + kg*8);
        hf8 bf3 = *(const hf8*)(h1c + 96 + kg*8);

        if (!l2w){
            ff4 acc[8];
            #pragma unroll
            for (int i = 0; i < 8; ++i)
                acc[i] = *(const ff4*)&xg[trow][(4*(8*wave+i)+kg) ^ sx][0];
            #pragma unroll
            for (int kt = 0; kt < 4; ++kt){
                hf8 bb = (kt==0)?bf0:(kt==1)?bf1:(kt==2)?bf2:bf3;
                #pragma unroll
                for (int i = 0; i < 8; ++i)
                    acc[i] = __builtin_amdgcn_mfma_f32_16x16x32_f16(A[i*4+kt], bb, acc[i], 0, 0, 0);
            }
            ff4 m0 = (rho & 1) ? acc[1] : acc[0];
            ff4 m1 = (rho & 1) ? acc[3] : acc[2];
            ff4 m2 = (rho & 1) ? acc[5] : acc[4];
            ff4 m3 = (rho & 1) ? acc[7] : acc[6];
            ff4 n0 = (rho & 2) ? m1 : m0;
            ff4 n1 = (rho & 2) ? m3 : m2;
            ff4 qd = (rho & 4) ? n1 : n0;
            float ig = sigm(qd[0]), fg = sigm(qd[1]);
            float gg = tanh_f(qd[2]), og = sigm(qd[3]);
            c = fg*c + ig*gg;
            float hv = og * tanh_f(c);
            if (rho < 8) h1buf[cur ^ 1][4*(8*wave + rho) + kg] = (f16)hv;
        } else {
            hf8 bf4 = *(const hf8*)(h2c      + kg*8);
            hf8 bf5 = *(const hf8*)(h2c + 32 + kg*8);
            ff4 acc[4];
            #pragma unroll
            for (int i = 0; i < 4; ++i) acc[i] = bias2[i];
            #pragma unroll
            for (int kt = 0; kt < 6; ++kt){
                hf8 bb = (kt==0)?bf0:(kt==1)?bf1:(kt==2)?bf2:(kt==3)?bf3:(kt==4)?bf4:bf5;
                #pragma unroll
                for (int i = 0; i < 4; ++i)
                    acc[i] = __builtin_amdgcn_mfma_f32_16x16x32_f16(A[i*6+kt], bb, acc[i], 0, 0, 0);
            }
            ff4 m0 = (rho & 1) ? acc[1] : acc[0];
            ff4 m1 = (rho & 1) ? acc[3] : acc[2];
            ff4 qd = (rho & 2) ? m1 : m0;
            float hv;
            if (t > 0){
                float ig = sigm(qd[0]), fg = sigm(qd[1]);
                float gg = tanh_f(qd[2]), og = sigm(qd[3]);
                c = fg*c + ig*gg;
                hv = og * tanh_f(c);
            } else {
                hv = 0.0f;                  // h2_{-1}=0, c2 untouched
            }
            if (rho < 4) h2buf[cur ^ 1][4*(4*(wave-4) + rho) + kg] = (f16)hv;
        }

        // ---- chunk GEMM for next 16 steps (xg single-buffer: extra barrier) ----
        if (trow == 15 && t + 1 < TT){
            __syncthreads();               // all xg[t] reads done before overwrite
            hf8 xh0 = cvt8(xl0, xl1);
            hf8 xh1 = cvt8(xl2, xl3);
            ff4 g0 = biasX[0], g1 = biasX[1], g2 = biasX[2], g3 = biasX[3];
            g0 = __builtin_amdgcn_mfma_f32_16x16x32_f16(AX[0], xh0, g0, 0, 0, 0);
            g1 = __builtin_amdgcn_mfma_f32_16x16x32_f16(AX[2], xh0, g1, 0, 0, 0);
            g2 = __builtin_amdgcn_mfma_f32_16x16x32_f16(AX[4], xh0, g2, 0, 0, 0);
            g3 = __builtin_amdgcn_mfma_f32_16x16x32_f16(AX[6], xh0, g3, 0, 0, 0);
            g0 = __builtin_amdgcn_mfma_f32_16x16x32_f16(AX[1], xh1, g0, 0, 0, 0);
            g1 = __builtin_amdgcn_mfma_f32_16x16x32_f16(AX[3], xh1, g1, 0, 0, 0);
            g2 = __builtin_amdgcn_mfma_f32_16x16x32_f16(AX[5], xh1, g2, 0, 0, 0);
            g3 = __builtin_amdgcn_mfma_f32_16x16x32_f16(AX[7], xh1, g3, 0, 0, 0);
            const int sw = rho & 7;
            *(ff4*)&xg[rho][(4*(4*wave+0)+kg) ^ sw][0] = g0;
            *(ff4*)&xg[rho][(4*(4*wave+1)+kg) ^ sw][0] = g1;
            *(ff4*)&xg[rho][(4*(4*wave+2)+kg) ^ sw][0] = g2;
            *(ff4*)&xg[rho][(4*(4*wave+3)+kg) ^ sw][0] = g3;
        }
        __syncthreads();
        cur ^= 1;
    }
    // after loop: cur==0; h1buf[0]=h1_{TT-1}, h2buf[0]=h2_{TT-2}

    // ---- epilogue: L2 step TT-1 ----
    if (l2w){
        const f16* h1c = h1buf[0];
        const f16* h2c = h2buf[0];
        hf8 bf0 = *(const hf8*)(h1c      + kg*8);
        hf8 bf1 = *(const hf8*)(h1c + 32 + kg*8);
        hf8 bf2 = *(const hf8*)(h1c + 64 + kg*8);
        hf8 bf3 = *(const hf8*)(h1c + 96 + kg*8);
        hf8 bf4 = *(const hf8*)(h2c      + kg*8);
        hf8 bf5 = *(const hf8*)(h2c + 32 + kg*8);
        ff4 acc[4];
        #pragma unroll
        for (int i = 0; i < 4; ++i) acc[i] = bias2[i];
        #pragma unroll
        for (int kt = 0; kt < 6; ++kt){
            hf8 bb = (kt==0)?bf0:(kt==1)?bf1:(kt==2)?bf2:(kt==3)?bf3:(kt==4)?bf4:bf5;
            #pragma unroll
            for (int i = 0; i < 4; ++i)
                acc[i] = __builtin_amdgcn_mfma_f32_16x16x32_f16(A[i*6+kt], bb, acc[i], 0, 0, 0);
        }
        ff4 m0 = (rho & 1) ? acc[1] : acc[0];
        ff4 m1 = (rho & 1) ? acc[3] : acc[2];
        ff4 qd = (rho & 2) ? m1 : m0;
        float ig = sigm(qd[0]), fg = sigm(qd[1]);
        float gg = tanh_f(qd[2]), og = sigm(qd[3]);
        c = fg*c + ig*gg;
        float hv = og * tanh_f(c);
        if (rho < 4) h2buf[1][4*(4*(wave-4) + rho) + kg] = (f16)hv;
    }
    __syncthreads();

    // ---- MLP head (final h2 in h2buf[1]) ----
    if (j < 32){
        float a = b1[j];
        const float* w = W1 + j*64;
        #pragma unroll
        for (int k = 0; k < 64; ++k) a = fmaf(w[k], (float)h2buf[1][k], a);
        headbuf[j] = sigm(a);
    }
    __syncthreads();
    if (j == 0){
        float a = b2[0];
        #pragma unroll
        for (int k = 0; k < 32; ++k) a = fmaf(W2[k], headbuf[k], a);
        out[b] = sigm(a);
    }
}

extern "C" void kernel_launch(void* const* d_in, const int* in_sizes, int n_in,
                              void* d_out, int out_size, void* d_ws, size_t ws_size,
                              hipStream_t stream)
{
    (void)in_sizes; (void)n_in; (void)d_ws; (void)ws_size; (void)out_size;
    lstm_mfma<<<NB, NT, 0, stream>>>(
        (const float*)d_in[0],
        (const float*)d_in[1], (const float*)d_in[2],
        (const float*)d_in[3], (const float*)d_in[4],
        (const float*)d_in[5], (const float*)d_in[6],
        (const float*)d_in[7], (const float*)d_in[8],
        (const float*)d_in[9], (const float*)d_in[10],
        (const float*)d_in[11], (const float*)d_in[12],
        (float*)d_out);
}